// Round 1
// baseline (471.097 us; speedup 1.0000x reference)
//
#include <hip/hip_runtime.h>

#define NN 8192
#define DD 256
#define CHUNK 1024

// Kernel 1: scores[row] = dot(inputs[row,:], H_v)   (one wave of 64 per row)
__global__ __launch_bounds__(256) void scores_kernel(const float* __restrict__ inputs,
                                                     const float* __restrict__ Hv,
                                                     float* __restrict__ scores) {
    int wave = threadIdx.x >> 6;
    int lane = threadIdx.x & 63;
    int row  = blockIdx.x * 4 + wave;
    if (row >= NN) return;
    // 64 lanes x float4 = 256 elements
    float4 v = ((const float4*)(inputs + (size_t)row * DD))[lane];
    float4 h = ((const float4*)Hv)[lane];
    float s = v.x * h.x + v.y * h.y + v.z * h.z + v.w * h.w;
    #pragma unroll
    for (int off = 32; off > 0; off >>= 1) s += __shfl_down(s, off, 64);
    if (lane == 0) scores[row] = s;
}

// Kernel 2: one block (256 threads) per row i.
// Scan adj row in CHUNK-sized pieces, compact nonzeros (j, e=exp(adj*score[j]))
// into LDS, then every thread d accumulates sum_j e_j * inputs[j][d].
// No max-subtraction needed: adj in [0.1,1], |score| <~ 8 -> exp is safe in fp32,
// and the softmax ratio is identical to the reference's max-shifted version.
__global__ __launch_bounds__(256) void attn_kernel(const float* __restrict__ adj,
                                                   const float* __restrict__ inputs,
                                                   const float* __restrict__ scores,
                                                   float* __restrict__ out) {
    __shared__ int   s_j[CHUNK];
    __shared__ float s_e[CHUNK];
    __shared__ int   s_cnt;

    const int row = blockIdx.x;
    const int tid = threadIdx.x;
    const float* __restrict__ arow = adj + (size_t)row * NN;

    float acc  = 0.0f;  // out[row][tid] numerator
    float ssum = 0.0f;  // softmax denominator (every thread computes it redundantly)

    for (int base = 0; base < NN; base += CHUNK) {
        if (tid == 0) s_cnt = 0;
        __syncthreads();

        // Each thread loads 4 contiguous floats of the adj row.
        float4 a = ((const float4*)(arow + base))[tid];
        int j0 = base + tid * 4;
        if (a.x != 0.0f) { int k = atomicAdd(&s_cnt, 1); s_j[k] = j0 + 0; s_e[k] = __expf(a.x * scores[j0 + 0]); }
        if (a.y != 0.0f) { int k = atomicAdd(&s_cnt, 1); s_j[k] = j0 + 1; s_e[k] = __expf(a.y * scores[j0 + 1]); }
        if (a.z != 0.0f) { int k = atomicAdd(&s_cnt, 1); s_j[k] = j0 + 2; s_e[k] = __expf(a.z * scores[j0 + 2]); }
        if (a.w != 0.0f) { int k = atomicAdd(&s_cnt, 1); s_j[k] = j0 + 3; s_e[k] = __expf(a.w * scores[j0 + 3]); }
        __syncthreads();

        const int cnt = s_cnt;
        // Broadcast LDS reads (same address across wave -> no bank conflict),
        // coalesced global gather of inputs columns.
        for (int k = 0; k < cnt; ++k) {
            float e = s_e[k];
            int   j = s_j[k];
            acc  += e * inputs[(size_t)j * DD + tid];
            ssum += e;
        }
        __syncthreads();
    }

    float r = (ssum > 0.0f) ? (acc / ssum) : 0.0f;
    out[(size_t)row * DD + tid] = r;
}

extern "C" void kernel_launch(void* const* d_in, const int* in_sizes, int n_in,
                              void* d_out, int out_size, void* d_ws, size_t ws_size,
                              hipStream_t stream) {
    const float* inputs = (const float*)d_in[0];  // [N, D] fp32
    const float* adj    = (const float*)d_in[1];  // [N, N] fp32
    const float* Hv     = (const float*)d_in[2];  // [D, 1] fp32
    float* out = (float*)d_out;                   // [N, D] fp32
    float* scores = (float*)d_ws;                 // N floats of scratch

    scores_kernel<<<NN / 4, 256, 0, stream>>>(inputs, Hv, scores);
    attn_kernel<<<NN, 256, 0, stream>>>(adj, inputs, scores, out);
}

// Round 2
// 432.837 us; speedup vs baseline: 1.0884x; 1.0884x over previous
//
#include <hip/hip_runtime.h>

#define NN 8192
#define DD 256
#define CAP 2048

// Kernel 1: scores[row] = dot(inputs[row,:], H_v)   (one wave of 64 per row)
__global__ __launch_bounds__(256) void scores_kernel(const float* __restrict__ inputs,
                                                     const float* __restrict__ Hv,
                                                     float* __restrict__ scores) {
    int wave = threadIdx.x >> 6;
    int lane = threadIdx.x & 63;
    int row  = blockIdx.x * 4 + wave;
    if (row >= NN) return;
    float4 v = ((const float4*)(inputs + (size_t)row * DD))[lane];
    float4 h = ((const float4*)Hv)[lane];
    float s = v.x * h.x + v.y * h.y + v.z * h.z + v.w * h.w;
    #pragma unroll
    for (int off = 32; off > 0; off >>= 1) s += __shfl_down(s, off, 64);
    if (lane == 0) scores[row] = s;
}

// Gather: wave `wave` handles compacted neighbors k = wave, wave+4, ...
// Each lane loads inputs[j][lane*4 .. lane*4+3] as float4 (16 B/lane, coalesced).
// 4-deep unroll -> 4 independent float4 loads in flight per wave.
__device__ __forceinline__ void gather_accum(const float2* s_je, int total,
                                             const float* __restrict__ inputs,
                                             int lane4, int wave,
                                             float4& acc, float& ssum) {
    int k = wave;
    for (; k + 12 < total; k += 16) {
        float2 je0 = s_je[k];
        float2 je1 = s_je[k + 4];
        float2 je2 = s_je[k + 8];
        float2 je3 = s_je[k + 12];
        const float4 v0 = *(const float4*)(inputs + (size_t)__float_as_int(je0.x) * DD + lane4);
        const float4 v1 = *(const float4*)(inputs + (size_t)__float_as_int(je1.x) * DD + lane4);
        const float4 v2 = *(const float4*)(inputs + (size_t)__float_as_int(je2.x) * DD + lane4);
        const float4 v3 = *(const float4*)(inputs + (size_t)__float_as_int(je3.x) * DD + lane4);
        acc.x += je0.y * v0.x; acc.y += je0.y * v0.y; acc.z += je0.y * v0.z; acc.w += je0.y * v0.w;
        acc.x += je1.y * v1.x; acc.y += je1.y * v1.y; acc.z += je1.y * v1.z; acc.w += je1.y * v1.w;
        acc.x += je2.y * v2.x; acc.y += je2.y * v2.y; acc.z += je2.y * v2.z; acc.w += je2.y * v2.w;
        acc.x += je3.y * v3.x; acc.y += je3.y * v3.y; acc.z += je3.y * v3.z; acc.w += je3.y * v3.w;
        ssum += je0.y + je1.y + je2.y + je3.y;
    }
    for (; k < total; k += 4) {
        float2 je = s_je[k];
        const float4 v = *(const float4*)(inputs + (size_t)__float_as_int(je.x) * DD + lane4);
        acc.x += je.y * v.x; acc.y += je.y * v.y; acc.z += je.y * v.z; acc.w += je.y * v.w;
        ssum += je.y;
    }
}

__global__ __launch_bounds__(256) void attn_kernel(const float* __restrict__ adj,
                                                   const float* __restrict__ inputs,
                                                   const float* __restrict__ scores,
                                                   float* __restrict__ out) {
    __shared__ float2 s_je[CAP];
    __shared__ int   s_wsum[4];
    __shared__ float s_ssum[4];
    __shared__ int   s_cnt;
    __shared__ float s_red[4 * DD];

    const int row   = blockIdx.x;
    const int tid   = threadIdx.x;
    const int lane  = tid & 63;
    const int wave  = tid >> 6;
    const int lane4 = lane * 4;

    // Preload the whole adj row slice into registers: all 8 float4 loads in flight at once.
    const float4* arow4 = (const float4*)(adj + (size_t)row * NN);
    float4 a[8];
#pragma unroll
    for (int c = 0; c < 8; ++c) a[c] = arow4[c * 256 + tid];

    // Count nonzeros per thread across all 32 elements.
    int nz = 0;
#pragma unroll
    for (int c = 0; c < 8; ++c)
        nz += (a[c].x != 0.f) + (a[c].y != 0.f) + (a[c].z != 0.f) + (a[c].w != 0.f);

    // Inclusive wave scan (6 shuffle steps), then cross-wave offsets via LDS.
    int pre = nz;
#pragma unroll
    for (int off = 1; off < 64; off <<= 1) {
        int t = __shfl_up(pre, off, 64);
        if (lane >= off) pre += t;
    }
    if (lane == 63) s_wsum[wave] = pre;
    __syncthreads();
    int base = 0, total = 0;
#pragma unroll
    for (int w = 0; w < 4; ++w) {
        int t = s_wsum[w];
        if (w < wave) base += t;
        total += t;
    }

    float4 acc = make_float4(0.f, 0.f, 0.f, 0.f);
    float ssum = 0.f;

    if (total <= CAP) {
        // Fast path: each thread writes its entries contiguously (order-free sum).
        int off = base + pre - nz;
#pragma unroll
        for (int c = 0; c < 8; ++c) {
            int j0 = c * 1024 + tid * 4;
            float v;
            v = a[c].x; if (v != 0.f) { s_je[off++] = make_float2(__int_as_float(j0 + 0), __expf(v * scores[j0 + 0])); }
            v = a[c].y; if (v != 0.f) { s_je[off++] = make_float2(__int_as_float(j0 + 1), __expf(v * scores[j0 + 1])); }
            v = a[c].z; if (v != 0.f) { s_je[off++] = make_float2(__int_as_float(j0 + 2), __expf(v * scores[j0 + 2])); }
            v = a[c].w; if (v != 0.f) { s_je[off++] = make_float2(__int_as_float(j0 + 3), __expf(v * scores[j0 + 3])); }
        }
        __syncthreads();
        gather_accum(s_je, total, inputs, lane4, wave, acc, ssum);
    } else {
        // Slow path (never expected at 2% density, guarantees any-density correctness):
        // per-chunk atomic compaction + flush; each chunk has <= 1024 entries <= CAP.
        for (int c = 0; c < 8; ++c) {
            if (tid == 0) s_cnt = 0;
            __syncthreads();
            int j0 = c * 1024 + tid * 4;
            float v;
            v = a[c].x; if (v != 0.f) { int k = atomicAdd(&s_cnt, 1); s_je[k] = make_float2(__int_as_float(j0 + 0), __expf(v * scores[j0 + 0])); }
            v = a[c].y; if (v != 0.f) { int k = atomicAdd(&s_cnt, 1); s_je[k] = make_float2(__int_as_float(j0 + 1), __expf(v * scores[j0 + 1])); }
            v = a[c].z; if (v != 0.f) { int k = atomicAdd(&s_cnt, 1); s_je[k] = make_float2(__int_as_float(j0 + 2), __expf(v * scores[j0 + 2])); }
            v = a[c].w; if (v != 0.f) { int k = atomicAdd(&s_cnt, 1); s_je[k] = make_float2(__int_as_float(j0 + 3), __expf(v * scores[j0 + 3])); }
            __syncthreads();
            gather_accum(s_je, s_cnt, inputs, lane4, wave, acc, ssum);
            __syncthreads();
        }
    }

    // Cross-wave reduction: wave w, lane l holds columns [l*4, l*4+4) partial sums.
    if (lane == 0) s_ssum[wave] = ssum;
    *(float4*)&s_red[wave * DD + lane4] = acc;
    __syncthreads();
    float tot = s_ssum[0] + s_ssum[1] + s_ssum[2] + s_ssum[3];
    float r = s_red[0 * DD + tid] + s_red[1 * DD + tid] + s_red[2 * DD + tid] + s_red[3 * DD + tid];
    out[(size_t)row * DD + tid] = (tot > 0.f) ? r / tot : 0.f;
}

extern "C" void kernel_launch(void* const* d_in, const int* in_sizes, int n_in,
                              void* d_out, int out_size, void* d_ws, size_t ws_size,
                              hipStream_t stream) {
    const float* inputs = (const float*)d_in[0];  // [N, D] fp32
    const float* adj    = (const float*)d_in[1];  // [N, N] fp32
    const float* Hv     = (const float*)d_in[2];  // [D, 1] fp32
    float* out = (float*)d_out;                   // [N, D] fp32
    float* scores = (float*)d_ws;                 // N floats of scratch

    scores_kernel<<<NN / 4, 256, 0, stream>>>(inputs, Hv, scores);
    attn_kernel<<<NN, 256, 0, stream>>>(adj, inputs, scores, out);
}

// Round 4
// 417.367 us; speedup vs baseline: 1.1287x; 1.0371x over previous
//
#include <hip/hip_runtime.h>

#define NN 8192
#define DD 256
#define CAP 1024

typedef float v4f __attribute__((ext_vector_type(4)));
typedef unsigned short u16x4 __attribute__((ext_vector_type(4)));

// ---------- prep kernels ----------

// scores[row] = dot(inputs[row,:], H_v)   (one wave of 64 per row)
__global__ __launch_bounds__(256) void scores_kernel(const float* __restrict__ inputs,
                                                     const float* __restrict__ Hv,
                                                     float* __restrict__ scores) {
    int wave = threadIdx.x >> 6;
    int lane = threadIdx.x & 63;
    int row  = blockIdx.x * 4 + wave;
    if (row >= NN) return;
    float4 v = ((const float4*)(inputs + (size_t)row * DD))[lane];
    float4 h = ((const float4*)Hv)[lane];
    float s = v.x * h.x + v.y * h.y + v.z * h.z + v.w * h.w;
    #pragma unroll
    for (int off = 32; off > 0; off >>= 1) s += __shfl_down(s, off, 64);
    if (lane == 0) scores[row] = s;
}

__device__ __forceinline__ unsigned short f2bf_rne(float x) {
    unsigned u = __float_as_uint(x);
    u += 0x7fffu + ((u >> 16) & 1u);
    return (unsigned short)(u >> 16);
}

// inputs fp32 [N,D] -> bf16 copy in workspace (halves gather traffic; 4 MB fits L2 better)
__global__ __launch_bounds__(256) void cvt_kernel(const float* __restrict__ inputs,
                                                  unsigned short* __restrict__ ib) {
    int idx = blockIdx.x * 256 + threadIdx.x;   // one float4 per thread
    float4 v = ((const float4*)inputs)[idx];
    u16x4 u;
    u.x = f2bf_rne(v.x); u.y = f2bf_rne(v.y); u.z = f2bf_rne(v.z); u.w = f2bf_rne(v.w);
    ((u16x4*)ib)[idx] = u;
}

// ---------- gather ----------

__device__ __forceinline__ float4 bf4_to_f4(u16x4 u) {
    float4 r;
    r.x = __uint_as_float((unsigned)u.x << 16);
    r.y = __uint_as_float((unsigned)u.y << 16);
    r.z = __uint_as_float((unsigned)u.z << 16);
    r.w = __uint_as_float((unsigned)u.w << 16);
    return r;
}

template <bool BF16>
__device__ __forceinline__ float4 load_row4(const float* __restrict__ inputs,
                                            const unsigned short* __restrict__ ib,
                                            int j, int lane4) {
    if (BF16) {
        return bf4_to_f4(*(const u16x4*)(ib + (size_t)j * DD + lane4));
    } else {
        return *(const float4*)(inputs + (size_t)j * DD + lane4);
    }
}

// Wave `wave` handles compacted neighbors k = wave, wave+4, ... 8-deep unroll.
template <bool BF16>
__device__ __forceinline__ void gather_accum(const float2* s_je, int total,
                                             const float* __restrict__ inputs,
                                             const unsigned short* __restrict__ ib,
                                             int lane4, int wave,
                                             float4& acc, float& ssum) {
    int k = wave;
    for (; k + 28 < total; k += 32) {
        float2 je[8];
        #pragma unroll
        for (int u = 0; u < 8; ++u) je[u] = s_je[k + 4 * u];
        float4 v[8];
        #pragma unroll
        for (int u = 0; u < 8; ++u) v[u] = load_row4<BF16>(inputs, ib, __float_as_int(je[u].x), lane4);
        #pragma unroll
        for (int u = 0; u < 8; ++u) {
            float e = je[u].y;
            acc.x += e * v[u].x; acc.y += e * v[u].y; acc.z += e * v[u].z; acc.w += e * v[u].w;
            ssum += e;
        }
    }
    for (; k < total; k += 4) {
        float2 je = s_je[k];
        float4 v = load_row4<BF16>(inputs, ib, __float_as_int(je.x), lane4);
        acc.x += je.y * v.x; acc.y += je.y * v.y; acc.z += je.y * v.z; acc.w += je.y * v.w;
        ssum += je.y;
    }
}

template <bool BF16>
__global__ __launch_bounds__(256) void attn_kernel(const float* __restrict__ adj,
                                                   const float* __restrict__ inputs,
                                                   const unsigned short* __restrict__ ib,
                                                   const float* __restrict__ scores,
                                                   float* __restrict__ out) {
    __shared__ float2 s_je[CAP];
    __shared__ int   s_wsum[4];
    __shared__ float s_ssum[4];
    __shared__ int   s_cnt;
    __shared__ float s_red[4 * DD];

    const int row   = blockIdx.x;
    const int tid   = threadIdx.x;
    const int lane  = tid & 63;
    const int wave  = tid >> 6;
    const int lane4 = lane * 4;

    // Stream the adj row with NON-TEMPORAL loads: single-use data, don't evict
    // inputs from L2/L3. (nt LOADS of immutable data are coherence-safe; the nt
    // STORE of `out` was removed — it caused post-timing divergence in R3.)
    const v4f* arow4 = (const v4f*)(adj + (size_t)row * NN);
    v4f a[8];
#pragma unroll
    for (int c = 0; c < 8; ++c) a[c] = __builtin_nontemporal_load(&arow4[c * 256 + tid]);

    int nz = 0;
#pragma unroll
    for (int c = 0; c < 8; ++c)
        nz += (a[c].x != 0.f) + (a[c].y != 0.f) + (a[c].z != 0.f) + (a[c].w != 0.f);

    // Inclusive wave scan, then cross-wave offsets via LDS.
    int pre = nz;
#pragma unroll
    for (int off = 1; off < 64; off <<= 1) {
        int t = __shfl_up(pre, off, 64);
        if (lane >= off) pre += t;
    }
    if (lane == 63) s_wsum[wave] = pre;
    __syncthreads();
    int base = 0, total = 0;
#pragma unroll
    for (int w = 0; w < 4; ++w) {
        int t = s_wsum[w];
        if (w < wave) base += t;
        total += t;
    }

    float4 acc = make_float4(0.f, 0.f, 0.f, 0.f);
    float ssum = 0.f;

    if (total <= CAP) {
        int off = base + pre - nz;
#pragma unroll
        for (int c = 0; c < 8; ++c) {
            int j0 = c * 1024 + tid * 4;
            float v;
            v = a[c].x; if (v != 0.f) { s_je[off++] = make_float2(__int_as_float(j0 + 0), __expf(v * scores[j0 + 0])); }
            v = a[c].y; if (v != 0.f) { s_je[off++] = make_float2(__int_as_float(j0 + 1), __expf(v * scores[j0 + 1])); }
            v = a[c].z; if (v != 0.f) { s_je[off++] = make_float2(__int_as_float(j0 + 2), __expf(v * scores[j0 + 2])); }
            v = a[c].w; if (v != 0.f) { s_je[off++] = make_float2(__int_as_float(j0 + 3), __expf(v * scores[j0 + 3])); }
        }
        __syncthreads();
        gather_accum<BF16>(s_je, total, inputs, ib, lane4, wave, acc, ssum);
    } else {
        // Slow path (any-density correctness): per-chunk atomic compaction + flush.
        for (int c = 0; c < 8; ++c) {
            if (tid == 0) s_cnt = 0;
            __syncthreads();
            int j0 = c * 1024 + tid * 4;
            float v;
            v = a[c].x; if (v != 0.f) { int k = atomicAdd(&s_cnt, 1); s_je[k] = make_float2(__int_as_float(j0 + 0), __expf(v * scores[j0 + 0])); }
            v = a[c].y; if (v != 0.f) { int k = atomicAdd(&s_cnt, 1); s_je[k] = make_float2(__int_as_float(j0 + 1), __expf(v * scores[j0 + 1])); }
            v = a[c].z; if (v != 0.f) { int k = atomicAdd(&s_cnt, 1); s_je[k] = make_float2(__int_as_float(j0 + 2), __expf(v * scores[j0 + 2])); }
            v = a[c].w; if (v != 0.f) { int k = atomicAdd(&s_cnt, 1); s_je[k] = make_float2(__int_as_float(j0 + 3), __expf(v * scores[j0 + 3])); }
            __syncthreads();
            gather_accum<BF16>(s_je, s_cnt, inputs, ib, lane4, wave, acc, ssum);
            __syncthreads();
        }
    }

    // Cross-wave reduction.
    if (lane == 0) s_ssum[wave] = ssum;
    *(float4*)&s_red[wave * DD + lane4] = acc;
    __syncthreads();
    float tot = s_ssum[0] + s_ssum[1] + s_ssum[2] + s_ssum[3];
    float r = s_red[0 * DD + tid] + s_red[1 * DD + tid] + s_red[2 * DD + tid] + s_red[3 * DD + tid];
    out[(size_t)row * DD + tid] = (tot > 0.f) ? r / tot : 0.f;
}

extern "C" void kernel_launch(void* const* d_in, const int* in_sizes, int n_in,
                              void* d_out, int out_size, void* d_ws, size_t ws_size,
                              hipStream_t stream) {
    const float* inputs = (const float*)d_in[0];  // [N, D] fp32
    const float* adj    = (const float*)d_in[1];  // [N, N] fp32
    const float* Hv     = (const float*)d_in[2];  // [D, 1] fp32
    float* out = (float*)d_out;                   // [N, D] fp32

    float* scores = (float*)d_ws;                             // 32 KB
    unsigned short* ib = (unsigned short*)((char*)d_ws + NN * sizeof(float));  // 4 MB bf16 copy

    const size_t need = NN * sizeof(float) + (size_t)NN * DD * sizeof(unsigned short);

    scores_kernel<<<NN / 4, 256, 0, stream>>>(inputs, Hv, scores);
    if (ws_size >= need) {
        cvt_kernel<<<(NN * DD / 4) / 256, 256, 0, stream>>>(inputs, ib);
        attn_kernel<true><<<NN, 256, 0, stream>>>(adj, inputs, ib, scores, out);
    } else {
        attn_kernel<false><<<NN, 256, 0, stream>>>(adj, inputs, (const unsigned short*)nullptr, scores, out);
    }
}

// Round 5
// 405.257 us; speedup vs baseline: 1.1625x; 1.0299x over previous
//
#include <hip/hip_runtime.h>

#define NN 8192
#define DD 256
#define CAP 1024

typedef float v4f __attribute__((ext_vector_type(4)));
typedef unsigned short u16x4 __attribute__((ext_vector_type(4)));

__device__ __forceinline__ unsigned short f2bf_rne(float x) {
    unsigned u = __float_as_uint(x);
    u += 0x7fffu + ((u >> 16) & 1u);
    return (unsigned short)(u >> 16);
}

__device__ __forceinline__ float4 bf4_to_f4(u16x4 u) {
    float4 r;
    r.x = __uint_as_float((unsigned)u.x << 16);
    r.y = __uint_as_float((unsigned)u.y << 16);
    r.z = __uint_as_float((unsigned)u.z << 16);
    r.w = __uint_as_float((unsigned)u.w << 16);
    return r;
}

// Fused prep: scores[row] = inputs[row,:].Hv AND bf16 copy of inputs (one read).
__global__ __launch_bounds__(256) void prep_kernel(const float* __restrict__ inputs,
                                                   const float* __restrict__ Hv,
                                                   float* __restrict__ scores,
                                                   unsigned short* __restrict__ ib) {
    int wave = threadIdx.x >> 6;
    int lane = threadIdx.x & 63;
    int row  = blockIdx.x * 4 + wave;
    float4 v = ((const float4*)(inputs + (size_t)row * DD))[lane];
    u16x4 u;
    u.x = f2bf_rne(v.x); u.y = f2bf_rne(v.y); u.z = f2bf_rne(v.z); u.w = f2bf_rne(v.w);
    ((u16x4*)(ib + (size_t)row * DD))[lane] = u;
    float4 h = ((const float4*)Hv)[lane];
    float s = v.x * h.x + v.y * h.y + v.z * h.z + v.w * h.w;
    #pragma unroll
    for (int off = 32; off > 0; off >>= 1) s += __shfl_down(s, off, 64);
    if (lane == 0) scores[row] = s;
}

template <bool BF16>
__device__ __forceinline__ float4 load_row4(const float* __restrict__ inputs,
                                            const unsigned short* __restrict__ ib,
                                            int j, int lane4) {
    if (BF16) return bf4_to_f4(*(const u16x4*)(ib + (size_t)j * DD + lane4));
    else      return *(const float4*)(inputs + (size_t)j * DD + lane4);
}

// Wave owns compacted entries [kbeg,kend). ONE ds_read_b64 per lane serves 64
// neighbors; (j,e) broadcast via v_readlane (VALU, no lgkmcnt in the chain).
template <bool BF16>
__device__ __forceinline__ void gather_accum(const float2* __restrict__ s_je,
                                             int kbeg, int kend,
                                             const float* __restrict__ inputs,
                                             const unsigned short* __restrict__ ib,
                                             int lane, int lane4,
                                             float4& acc, float& ssum) {
    for (int base = kbeg; base < kend; base += 64) {
        int nb = kend - base; nb = nb > 64 ? 64 : nb;
        float2 je = s_je[base + (lane < nb ? lane : 0)];
        int jl = __float_as_int(je.x);
        int el = __float_as_int(je.y);
        int m = 0;
        for (; m + 8 <= nb; m += 8) {
            int js[8]; float es[8]; float4 f[8];
            #pragma unroll
            for (int u = 0; u < 8; ++u) {
                js[u] = __builtin_amdgcn_readlane(jl, m + u);
                es[u] = __uint_as_float(__builtin_amdgcn_readlane(el, m + u));
            }
            #pragma unroll
            for (int u = 0; u < 8; ++u) f[u] = load_row4<BF16>(inputs, ib, js[u], lane4);
            #pragma unroll
            for (int u = 0; u < 8; ++u) {
                acc.x += es[u] * f[u].x; acc.y += es[u] * f[u].y;
                acc.z += es[u] * f[u].z; acc.w += es[u] * f[u].w;
                ssum  += es[u];
            }
        }
        for (; m < nb; ++m) {
            int   j = __builtin_amdgcn_readlane(jl, m);
            float e = __uint_as_float(__builtin_amdgcn_readlane(el, m));
            float4 f = load_row4<BF16>(inputs, ib, j, lane4);
            acc.x += e * f.x; acc.y += e * f.y; acc.z += e * f.z; acc.w += e * f.w;
            ssum += e;
        }
    }
}

template <bool BF16>
__global__ __launch_bounds__(256) void attn_kernel(const float* __restrict__ adj,
                                                   const float* __restrict__ inputs,
                                                   const unsigned short* __restrict__ ib,
                                                   const float* __restrict__ scores,
                                                   float* __restrict__ out) {
    __shared__ float2 s_je[CAP];
    __shared__ int   s_wsum[4];
    __shared__ float s_ssum[4];
    __shared__ int   s_cnt;
    __shared__ float s_red[4 * DD];

    const int row   = blockIdx.x;
    const int tid   = threadIdx.x;
    const int lane  = tid & 63;
    const int wave  = tid >> 6;
    const int lane4 = lane * 4;

    // Stream single-use adj with nt loads (keeps inputs resident in L2/L3).
    const v4f* arow4 = (const v4f*)(adj + (size_t)row * NN);
    v4f a[8];
#pragma unroll
    for (int c = 0; c < 8; ++c) a[c] = __builtin_nontemporal_load(&arow4[c * 256 + tid]);

    int nz = 0;
#pragma unroll
    for (int c = 0; c < 8; ++c)
        nz += (a[c].x != 0.f) + (a[c].y != 0.f) + (a[c].z != 0.f) + (a[c].w != 0.f);

    int pre = nz;
#pragma unroll
    for (int off = 1; off < 64; off <<= 1) {
        int t = __shfl_up(pre, off, 64);
        if (lane >= off) pre += t;
    }
    if (lane == 63) s_wsum[wave] = pre;
    __syncthreads();
    int base = 0, total = 0;
#pragma unroll
    for (int w = 0; w < 4; ++w) {
        int t = s_wsum[w];
        if (w < wave) base += t;
        total += t;
    }

    float4 acc = make_float4(0.f, 0.f, 0.f, 0.f);
    float ssum = 0.f;

    if (total <= CAP) {
        int off = base + pre - nz;
#pragma unroll
        for (int c = 0; c < 8; ++c) {
            int j0 = c * 1024 + tid * 4;
            float v;
            v = a[c].x; if (v != 0.f) { s_je[off++] = make_float2(__int_as_float(j0 + 0), __expf(v * scores[j0 + 0])); }
            v = a[c].y; if (v != 0.f) { s_je[off++] = make_float2(__int_as_float(j0 + 1), __expf(v * scores[j0 + 1])); }
            v = a[c].z; if (v != 0.f) { s_je[off++] = make_float2(__int_as_float(j0 + 2), __expf(v * scores[j0 + 2])); }
            v = a[c].w; if (v != 0.f) { s_je[off++] = make_float2(__int_as_float(j0 + 3), __expf(v * scores[j0 + 3])); }
        }
        __syncthreads();
        // Contiguous per-wave split of the compacted list.
        gather_accum<BF16>(s_je, wave * total / 4, (wave + 1) * total / 4,
                           inputs, ib, lane, lane4, acc, ssum);
    } else {
        // Slow path (any-density correctness): per-chunk atomic compaction + flush.
        for (int c = 0; c < 8; ++c) {
            if (tid == 0) s_cnt = 0;
            __syncthreads();
            int j0 = c * 1024 + tid * 4;
            float v;
            v = a[c].x; if (v != 0.f) { int k = atomicAdd(&s_cnt, 1); s_je[k] = make_float2(__int_as_float(j0 + 0), __expf(v * scores[j0 + 0])); }
            v = a[c].y; if (v != 0.f) { int k = atomicAdd(&s_cnt, 1); s_je[k] = make_float2(__int_as_float(j0 + 1), __expf(v * scores[j0 + 1])); }
            v = a[c].z; if (v != 0.f) { int k = atomicAdd(&s_cnt, 1); s_je[k] = make_float2(__int_as_float(j0 + 2), __expf(v * scores[j0 + 2])); }
            v = a[c].w; if (v != 0.f) { int k = atomicAdd(&s_cnt, 1); s_je[k] = make_float2(__int_as_float(j0 + 3), __expf(v * scores[j0 + 3])); }
            __syncthreads();
            int tc = s_cnt;
            gather_accum<BF16>(s_je, wave * tc / 4, (wave + 1) * tc / 4,
                               inputs, ib, lane, lane4, acc, ssum);
            __syncthreads();
        }
    }

    // Cross-wave reduction.
    if (lane == 0) s_ssum[wave] = ssum;
    *(float4*)&s_red[wave * DD + lane4] = acc;
    __syncthreads();
    float tot = s_ssum[0] + s_ssum[1] + s_ssum[2] + s_ssum[3];
    float r = s_red[0 * DD + tid] + s_red[1 * DD + tid] + s_red[2 * DD + tid] + s_red[3 * DD + tid];
    out[(size_t)row * DD + tid] = (tot > 0.f) ? r / tot : 0.f;
}

extern "C" void kernel_launch(void* const* d_in, const int* in_sizes, int n_in,
                              void* d_out, int out_size, void* d_ws, size_t ws_size,
                              hipStream_t stream) {
    const float* inputs = (const float*)d_in[0];  // [N, D] fp32
    const float* adj    = (const float*)d_in[1];  // [N, N] fp32
    const float* Hv     = (const float*)d_in[2];  // [D, 1] fp32
    float* out = (float*)d_out;                   // [N, D] fp32

    float* scores = (float*)d_ws;                                               // 32 KB
    unsigned short* ib = (unsigned short*)((char*)d_ws + NN * sizeof(float));   // 4 MB bf16 copy

    const size_t need = NN * sizeof(float) + (size_t)NN * DD * sizeof(unsigned short);

    if (ws_size >= need) {
        prep_kernel<<<NN / 4, 256, 0, stream>>>(inputs, Hv, scores, ib);
        attn_kernel<true><<<NN, 256, 0, stream>>>(adj, inputs, ib, scores, out);
    } else {
        prep_kernel<<<NN / 4, 256, 0, stream>>>(inputs, Hv, scores, ib /*unused*/);
        attn_kernel<false><<<NN, 256, 0, stream>>>(adj, inputs, (const unsigned short*)nullptr, scores, out);
    }
}